// Round 3
// baseline (1696.763 us; speedup 1.0000x reference)
//
#include <hip/hip_runtime.h>
#include <stdint.h>

#define N_TOK 256
#define D_MODEL 1024
#define VOCAB 128000
#define NV_ELEMS (256LL * 128000LL)

// ===================== JAX threefry2x32 (KAT-verified core) =====================
__device__ __forceinline__ uint32_t rotl32(uint32_t x, int d) {
    return (x << d) | (x >> (32 - d));
}

// key(42) -> key data [0, 42]
__device__ __forceinline__ uint2 tf_0_42(uint32_t c0, uint32_t c1) {
    const uint32_t ks0 = 0u, ks1 = 42u, ks2 = 0x1BD11BDAu ^ 42u;
    uint32_t x0 = c0 + ks0, x1 = c1 + ks1;
#define R4(a,b,c,d) \
    x0 += x1; x1 = rotl32(x1,a); x1 ^= x0; \
    x0 += x1; x1 = rotl32(x1,b); x1 ^= x0; \
    x0 += x1; x1 = rotl32(x1,c); x1 ^= x0; \
    x0 += x1; x1 = rotl32(x1,d); x1 ^= x0;
    R4(13,15,26,6)   x0 += ks1; x1 += ks2 + 1u;
    R4(17,29,16,24)  x0 += ks2; x1 += ks0 + 2u;
    R4(13,15,26,6)   x0 += ks0; x1 += ks1 + 3u;
    R4(17,29,16,24)  x0 += ks1; x1 += ks2 + 4u;
    R4(13,15,26,6)   x0 += ks2; x1 += ks0 + 5u;
#undef R4
    return make_uint2(x0, x1);
}

// PARTITIONABLE threefry bits (modern JAX default, jax_threefry_partitionable=True):
// counter = 64-bit flat index j -> words (hi32(j)=0, lo32(j)=j); 32-bit output = x ^ y.
__device__ __forceinline__ uint32_t jax_bits(uint32_t j) {
    uint2 r = tf_0_42(0u, j);
    return r.x ^ r.y;
}

__device__ __forceinline__ float jax_gumbel(uint32_t bits) {
    const float TINY = 1.17549435e-38f;
    float u = __uint_as_float((bits >> 9) | 0x3f800000u) - 1.0f;
    u = u + TINY;              // (maxval-minval)==1.0f in f32 => f*1+tiny
    u = fmaxf(TINY, u);
    return -logf(-logf(u));
}

// ===================== GEMM (f32 baseline, verified) =====================
// C[n][v] = sum_k hidden[idx[n]][k] * emb[v][k];  BM=64, BN=64, BK=16, 4x4/thread
__global__ __launch_bounds__(256) void gemm_kernel(
        const float* __restrict__ hidden, const int* __restrict__ idx,
        const float* __restrict__ emb, float* __restrict__ logits) {
    __shared__ float As[16][64];
    __shared__ float Bs[16][64];
    const int n0 = blockIdx.x * 64, v0 = blockIdx.y * 64;
    const int tid = threadIdx.x;
    const int tx = tid & 15, ty = tid >> 4;
    const int lr = tid >> 2, lk = (tid & 3) * 4;
    float acc[4][4] = {};
    const long long aRow = (long long)idx[n0 + lr] * D_MODEL + lk;
    const long long bRow = (long long)(v0 + lr) * D_MODEL + lk;
    for (int k0 = 0; k0 < D_MODEL; k0 += 16) {
        float4 av = *(const float4*)(hidden + aRow + k0);
        float4 bv = *(const float4*)(emb + bRow + k0);
        __syncthreads();
        As[lk + 0][lr] = av.x; As[lk + 1][lr] = av.y; As[lk + 2][lr] = av.z; As[lk + 3][lr] = av.w;
        Bs[lk + 0][lr] = bv.x; Bs[lk + 1][lr] = bv.y; Bs[lk + 2][lr] = bv.z; Bs[lk + 3][lr] = bv.w;
        __syncthreads();
#pragma unroll
        for (int kk = 0; kk < 16; ++kk) {
            float4 a = *(const float4*)&As[kk][ty * 4];
            float4 b = *(const float4*)&Bs[kk][tx * 4];
            float aa[4] = {a.x, a.y, a.z, a.w};
            float bb[4] = {b.x, b.y, b.z, b.w};
#pragma unroll
            for (int i = 0; i < 4; ++i)
#pragma unroll
                for (int j = 0; j < 4; ++j)
                    acc[i][j] += aa[i] * bb[j];
        }
    }
#pragma unroll
    for (int i = 0; i < 4; ++i) {
        float4 o = make_float4(acc[i][0], acc[i][1], acc[i][2], acc[i][3]);
        *(float4*)(logits + (long long)(n0 + ty * 4 + i) * VOCAB + (v0 + tx * 4)) = o;
    }
}

// ===================== fused per-row sampler =====================
// One block (1024 threads) per row. 128000 = 1024*125 exactly.
// probs[] holds logits on entry, probs_f on exit.
__global__ __launch_bounds__(1024) void sample_kernel(
        float* __restrict__ probs, const float* __restrict__ temps,
        const float* __restrict__ topps, float* __restrict__ outTok) {
    const int row = blockIdx.x;
    const int tid = (int)threadIdx.x;
    float* L = probs + (long long)row * VOCAB;

    __shared__ float hsum[2048];
    __shared__ uint32_t hcnt[2048];
    __shared__ float wred[16];
    __shared__ float aVal[16];
    __shared__ int aIdx[16];
    __shared__ uint32_t tieList[64];
    __shared__ float sM, sS, sSp, sCarry;
    __shared__ uint32_t sPref, sTsKey, sMt, sTieN;

    const float t = temps[row];
    const float p = topps[row];

    // ---- P1: M = max(l/t)
    float m = -INFINITY;
    for (int i = 0; i < 125; ++i) m = fmaxf(m, L[tid + i * 1024] / t);
    for (int o = 32; o >= 1; o >>= 1) m = fmaxf(m, __shfl_xor(m, o, 64));
    if ((tid & 63) == 0) wred[tid >> 6] = m;
    __syncthreads();
    if (tid == 0) {
        float mm = wred[0];
        for (int w = 1; w < 16; ++w) mm = fmaxf(mm, wred[w]);
        sM = mm;
    }
    __syncthreads();
    const float M = sM;

    // ---- P2: S = sum exp(l/t - M)
    float sacc0 = 0.0f;
    for (int i = 0; i < 125; ++i) sacc0 += expf(L[tid + i * 1024] / t - M);
    for (int o = 32; o >= 1; o >>= 1) sacc0 += __shfl_xor(sacc0, o, 64);
    if ((tid & 63) == 0) wred[tid >> 6] = sacc0;
    __syncthreads();
    if (tid == 0) {
        float ss = 0.0f;
        for (int w = 0; w < 16; ++w) ss += wred[w];
        sS = ss;
    }
    __syncthreads();
    const float S = sS;

    // ---- Level 1: bucket = key >> 20  (2048 buckets)
    for (int i = tid; i < 2048; i += 1024) { hsum[i] = 0.0f; hcnt[i] = 0u; }
    __syncthreads();
    for (int i = 0; i < 125; ++i) {
        int v = tid + i * 1024;
        float pv = expf(L[v] / t - M) / S;
        atomicAdd(&hsum[__float_as_uint(pv) >> 20], pv);
    }
    __syncthreads();
    if (tid == 0) {
        float sa = 0.0f; int cb = -1;
        for (int b = 2047; b >= 0; --b) {
            float h = hsum[b];
            if (sa + h > p) { cb = b; break; }
            sa += h;
        }
        if (cb < 0) { cb = 0; sa -= hsum[0]; }
        sPref = (uint32_t)cb; sCarry = sa;
    }
    __syncthreads();

    // ---- Level 2: among key>>20 == pref1, bucket = (key>>10)&1023
    {
        const uint32_t pref1 = sPref;
        hsum[tid & 1023] = 0.0f;
        hcnt[tid & 1023] = 0u;
        __syncthreads();
        for (int i = 0; i < 125; ++i) {
            int v = tid + i * 1024;
            float pv = expf(L[v] / t - M) / S;
            uint32_t key = __float_as_uint(pv);
            if ((key >> 20) == pref1) atomicAdd(&hsum[(key >> 10) & 1023u], pv);
        }
        __syncthreads();
        if (tid == 0) {
            float sa = sCarry; int cb = -1;
            for (int b = 1023; b >= 0; --b) {
                float h = hsum[b];
                if (sa + h > p) { cb = b; break; }
                sa += h;
            }
            if (cb < 0) { cb = 0; sa -= hsum[0]; }
            sPref = (sPref << 10) | (uint32_t)cb; sCarry = sa;
        }
        __syncthreads();
    }

    // ---- Level 3: among key>>10 == pref21, bucket = key & 1023; also counts
    {
        const uint32_t pref21 = sPref;
        hsum[tid & 1023] = 0.0f;
        hcnt[tid & 1023] = 0u;
        __syncthreads();
        for (int i = 0; i < 125; ++i) {
            int v = tid + i * 1024;
            float pv = expf(L[v] / t - M) / S;
            uint32_t key = __float_as_uint(pv);
            if ((key >> 10) == pref21) {
                atomicAdd(&hsum[key & 1023u], pv);
                atomicAdd(&hcnt[key & 1023u], 1u);
            }
        }
        __syncthreads();
        if (tid == 0) {
            float sa = sCarry; int cb = -1;
            for (int b = 1023; b >= 0; --b) {
                float h = hsum[b];
                if (sa + h > p) { cb = b; break; }
                sa += h;
            }
            if (cb < 0) { cb = 0; sa -= hsum[0]; }
            uint32_t ts = (sPref << 10) | (uint32_t)cb;
            uint32_t cnt = hcnt[cb]; if (cnt == 0u) cnt = 1u;
            float tf = __uint_as_float(ts);
            uint32_t mt;
            if (!(tf > 0.0f)) mt = cnt;
            else {
                float rem = p - sa; if (rem < 0.0f) rem = 0.0f;
                float q = floorf(rem / tf);
                mt = (q >= (float)(cnt - 1)) ? cnt : ((uint32_t)q + 1u);
            }
            sTsKey = ts; sMt = mt;
            sSp = sa + (float)mt * tf;
            sTieN = 0u;
        }
        __syncthreads();
    }

    // ---- tie index collection (stable-sort order = ascending index)
    const uint32_t ts = sTsKey;
    for (int i = 0; i < 125; ++i) {
        int v = tid + i * 1024;
        float pv = expf(L[v] / t - M) / S;
        if (__float_as_uint(pv) == ts) {
            uint32_t pos = atomicAdd(&sTieN, 1u);
            if (pos < 64u) tieList[pos] = (uint32_t)v;
        }
    }
    __syncthreads();

    // ---- final: write probs_f, gumbel-argmax
    const uint32_t mt = sMt;
    const float Sp = sSp;
    const uint32_t tn = min(sTieN, 64u);
    float bestV = -INFINITY;
    int bestI = 0x7FFFFFFF;
    for (int i = 0; i < 125; ++i) {
        int v = tid + i * 1024;
        float pv = expf(L[v] / t - M) / S;
        uint32_t key = __float_as_uint(pv);
        bool kept = key > ts;
        if (key == ts) {
            uint32_t rank = 0;
            for (uint32_t j = 0; j < tn; ++j) rank += (tieList[j] < (uint32_t)v) ? 1u : 0u;
            kept = rank < mt;
        }
        float pf = kept ? pv / Sp : 0.0f;
        L[v] = pf;
        uint32_t jj = (uint32_t)row * (uint32_t)VOCAB + (uint32_t)v;
        float g = jax_gumbel(jax_bits(jj));
        float val = logf(pf + 1e-20f) + g;
        if (val > bestV || (val == bestV && v < bestI)) { bestV = val; bestI = v; }
    }
    for (int o = 32; o >= 1; o >>= 1) {
        float ov = __shfl_xor(bestV, o, 64);
        int oi = __shfl_xor(bestI, o, 64);
        if (ov > bestV || (ov == bestV && oi < bestI)) { bestV = ov; bestI = oi; }
    }
    if ((tid & 63) == 0) { aVal[tid >> 6] = bestV; aIdx[tid >> 6] = bestI; }
    __syncthreads();
    if (tid == 0) {
        float bv = aVal[0]; int bi = aIdx[0];
        for (int w = 1; w < 16; ++w) {
            if (aVal[w] > bv || (aVal[w] == bv && aIdx[w] < bi)) { bv = aVal[w]; bi = aIdx[w]; }
        }
        outTok[row] = (float)bi;
    }
}

// ===================== launch =====================
extern "C" void kernel_launch(void* const* d_in, const int* in_sizes, int n_in,
                              void* d_out, int out_size, void* d_ws, size_t ws_size,
                              hipStream_t stream) {
    const float* hidden = (const float*)d_in[0];
    const float* emb    = (const float*)d_in[1];
    const float* temps  = (const float*)d_in[2];
    const float* topps  = (const float*)d_in[3];
    const int*   idx    = (const int*)d_in[4];

    float* probs  = (float*)d_out;        // [N,V]: logits, then probs_f in place
    float* outTok = probs + NV_ELEMS;     // [N] tokens as f32

    gemm_kernel<<<dim3(4, 2000), 256, 0, stream>>>(hidden, idx, emb, probs);
    sample_kernel<<<N_TOK, 1024, 0, stream>>>(probs, temps, topps, outTok);
}

// Round 4
// 1159.138 us; speedup vs baseline: 1.4638x; 1.4638x over previous
//
#include <hip/hip_runtime.h>
#include <stdint.h>

#define N_TOK 256
#define D_MODEL 1024
#define VOCAB 128000
#define NV_ELEMS (256LL * 128000LL)

typedef __attribute__((ext_vector_type(8))) short bfrag;   // 8 bf16 (4 VGPR)
typedef __attribute__((ext_vector_type(4))) float facc;    // 4 f32

// ===================== helpers =====================
__device__ __forceinline__ uint32_t bf16_rne_bits(float x) {
    uint32_t u = __float_as_uint(x);
    return (u + 0x7fffu + ((u >> 16) & 1u)) >> 16;
}

__device__ __forceinline__ uint32_t rotl32(uint32_t x, int d) {
    return (x << d) | (x >> (32 - d));
}

// JAX threefry2x32, key = (0,42) (KAT-verified core)
__device__ __forceinline__ uint2 tf_0_42(uint32_t c0, uint32_t c1) {
    const uint32_t ks0 = 0u, ks1 = 42u, ks2 = 0x1BD11BDAu ^ 42u;
    uint32_t x0 = c0 + ks0, x1 = c1 + ks1;
#define R4(a,b,c,d) \
    x0 += x1; x1 = rotl32(x1,a); x1 ^= x0; \
    x0 += x1; x1 = rotl32(x1,b); x1 ^= x0; \
    x0 += x1; x1 = rotl32(x1,c); x1 ^= x0; \
    x0 += x1; x1 = rotl32(x1,d); x1 ^= x0;
    R4(13,15,26,6)   x0 += ks1; x1 += ks2 + 1u;
    R4(17,29,16,24)  x0 += ks2; x1 += ks0 + 2u;
    R4(13,15,26,6)   x0 += ks0; x1 += ks1 + 3u;
    R4(17,29,16,24)  x0 += ks1; x1 += ks2 + 4u;
    R4(13,15,26,6)   x0 += ks2; x1 += ks0 + 5u;
#undef R4
    return make_uint2(x0, x1);
}

// partitionable threefry bits: counter = (0, j), output = x ^ y  (verified r3)
__device__ __forceinline__ uint32_t jax_bits(uint32_t j) {
    uint2 r = tf_0_42(0u, j);
    return r.x ^ r.y;
}

__device__ __forceinline__ float jax_gumbel(uint32_t bits) {
    const float TINY = 1.17549435e-38f;
    float u = __uint_as_float((bits >> 9) | 0x3f800000u) - 1.0f;
    u = u + TINY;
    u = fmaxf(TINY, u);
    return -logf(-logf(u));
}

// ===================== A pre-convert (gather + split-bf16 + swizzled image) ==
// Image layout (per 64-k K-tile, 65536 B): for row r(0..255), kgroup g(0..7),
// sel(hi=0,lo=16), elem e(0..7):
//   byte = kt*65536 + ((r*256 + g*32 + sel) ^ ((r&7)<<4)) + e*2
__global__ __launch_bounds__(256) void prep_a(
        const float* __restrict__ hidden, const int* __restrict__ idx,
        ushort* __restrict__ wsA) {
    const int m = blockIdx.x;
    const int t = threadIdx.x;
    const float* src = hidden + (long long)idx[m] * D_MODEL;
    const uint32_t swz = (uint32_t)((m & 7) << 4);
    for (int j = 0; j < 4; ++j) {
        int k = t * 4 + j;
        float x = src[k];
        uint32_t hb = bf16_rne_bits(x);
        float hf = __uint_as_float(hb << 16);
        uint32_t lb = bf16_rne_bits(x - hf);
        int kt = k >> 6, kk = k & 63, g = kk >> 3, e = kk & 7;
        char* img = (char*)wsA + (size_t)kt * 65536;
        uint32_t base = (uint32_t)(m * 256 + g * 32);
        *(ushort*)(img + ((base + 0) ^ swz) + e * 2) = (ushort)hb;
        *(ushort*)(img + ((base + 16) ^ swz) + e * 2) = (ushort)lb;
    }
}

// ===================== split-bf16 MFMA GEMM =====================
// C[m][v] = sum_k A[m][k]*B[v][k], BM=256 (all rows), BN=64, BK=64.
// 4 waves; wave w owns rows w*64..w*64+63 (4 m-frags x 4 n-frags of 16x16).
// 3 MFMAs per fragment pair: Ah*Bh + Ah*Bl + Al*Bh (f32 accumulate).
__global__ __launch_bounds__(256) void gemm_mfma(
        const ushort* __restrict__ wsA, const float* __restrict__ emb,
        float* __restrict__ logits) {
    __shared__ ushort Aimg[32768];  // 64 KB swizzled image (copied per K-tile)
    __shared__ ushort Bimg[8192];   // 16 KB swizzled B tile
    const int tid = (int)threadIdx.x;
    const int w = tid >> 6, l = tid & 63;
    const int lr = l & 15, lg = l >> 4;
    const int v0 = blockIdx.x * 64;
    char* Ab = (char*)Aimg;
    char* Bb = (char*)Bimg;

    facc acc[4][4] = {};

    for (int kt = 0; kt < 16; ++kt) {
        __syncthreads();
        // ---- stage A: linear 64 KB copy of the pre-swizzled image
        const char* asrc = (const char*)wsA + (size_t)kt * 65536;
#pragma unroll
        for (int i = 0; i < 16; ++i) {
            int off = i * 4096 + tid * 16;
            *(bfrag*)(Ab + off) = *(const bfrag*)(asrc + off);
        }
        // ---- stage B: load f32, split to bf16 hi/lo, swizzled ds_write_b128
#pragma unroll
        for (int uu = 0; uu < 2; ++uu) {
            int u = tid + uu * 256;             // 512 units = 64 rows x 8 kgroups
            int rb = u >> 3, g = u & 7;
            const float* bs = emb + (size_t)(v0 + rb) * D_MODEL + kt * 64 + g * 8;
            float4 x0 = *(const float4*)bs;
            float4 x1 = *(const float4*)(bs + 4);
            float xs[8] = {x0.x, x0.y, x0.z, x0.w, x1.x, x1.y, x1.z, x1.w};
            bfrag h, lo;
#pragma unroll
            for (int e = 0; e < 8; ++e) {
                uint32_t hb = bf16_rne_bits(xs[e]);
                float hf = __uint_as_float(hb << 16);
                uint32_t lb = bf16_rne_bits(xs[e] - hf);
                h[e] = (short)hb; lo[e] = (short)lb;
            }
            uint32_t swz = (uint32_t)((rb & 7) << 4);
            uint32_t base = (uint32_t)(rb * 256 + g * 32);
            *(bfrag*)(Bb + ((base + 0) ^ swz)) = h;
            *(bfrag*)(Bb + ((base + 16) ^ swz)) = lo;
        }
        __syncthreads();
        // ---- MFMA over 2 k-steps of 32
#pragma unroll
        for (int s = 0; s < 2; ++s) {
            const int g = s * 4 + lg;
            bfrag ah[4], al[4], bh[4], bl[4];
#pragma unroll
            for (int mi = 0; mi < 4; ++mi) {
                int r = w * 64 + mi * 16 + lr;
                uint32_t swz = (uint32_t)((r & 7) << 4);
                uint32_t base = (uint32_t)(r * 256 + g * 32);
                ah[mi] = *(const bfrag*)(Ab + ((base + 0) ^ swz));
                al[mi] = *(const bfrag*)(Ab + ((base + 16) ^ swz));
            }
#pragma unroll
            for (int nj = 0; nj < 4; ++nj) {
                int rb = nj * 16 + lr;
                uint32_t swz = (uint32_t)((rb & 7) << 4);
                uint32_t base = (uint32_t)(rb * 256 + g * 32);
                bh[nj] = *(const bfrag*)(Bb + ((base + 0) ^ swz));
                bl[nj] = *(const bfrag*)(Bb + ((base + 16) ^ swz));
            }
#pragma unroll
            for (int mi = 0; mi < 4; ++mi)
#pragma unroll
                for (int nj = 0; nj < 4; ++nj) {
                    acc[mi][nj] = __builtin_amdgcn_mfma_f32_16x16x32_bf16(
                        ah[mi], bh[nj], acc[mi][nj], 0, 0, 0);
                    acc[mi][nj] = __builtin_amdgcn_mfma_f32_16x16x32_bf16(
                        ah[mi], bl[nj], acc[mi][nj], 0, 0, 0);
                    acc[mi][nj] = __builtin_amdgcn_mfma_f32_16x16x32_bf16(
                        al[mi], bh[nj], acc[mi][nj], 0, 0, 0);
                }
        }
    }
    // ---- C write: frag row = lg*4+reg (M), col = lr (V)
#pragma unroll
    for (int mi = 0; mi < 4; ++mi) {
        int mbase = w * 64 + mi * 16 + lg * 4;
#pragma unroll
        for (int nj = 0; nj < 4; ++nj) {
            int v = v0 + nj * 16 + lr;
#pragma unroll
            for (int reg = 0; reg < 4; ++reg)
                logits[(size_t)(mbase + reg) * VOCAB + v] = acc[mi][nj][reg];
        }
    }
}

// ===================== f32 GEMM fallback (ws too small) =====================
__global__ __launch_bounds__(256) void gemm_kernel(
        const float* __restrict__ hidden, const int* __restrict__ idx,
        const float* __restrict__ emb, float* __restrict__ logits) {
    __shared__ float As[16][64];
    __shared__ float Bs[16][64];
    const int n0 = blockIdx.x * 64, v0 = blockIdx.y * 64;
    const int tid = threadIdx.x;
    const int tx = tid & 15, ty = tid >> 4;
    const int lr = tid >> 2, lk = (tid & 3) * 4;
    float acc[4][4] = {};
    const long long aRow = (long long)idx[n0 + lr] * D_MODEL + lk;
    const long long bRow = (long long)(v0 + lr) * D_MODEL + lk;
    for (int k0 = 0; k0 < D_MODEL; k0 += 16) {
        float4 av = *(const float4*)(hidden + aRow + k0);
        float4 bv = *(const float4*)(emb + bRow + k0);
        __syncthreads();
        As[lk + 0][lr] = av.x; As[lk + 1][lr] = av.y; As[lk + 2][lr] = av.z; As[lk + 3][lr] = av.w;
        Bs[lk + 0][lr] = bv.x; Bs[lk + 1][lr] = bv.y; Bs[lk + 2][lr] = bv.z; Bs[lk + 3][lr] = bv.w;
        __syncthreads();
#pragma unroll
        for (int kk = 0; kk < 16; ++kk) {
            float4 a = *(const float4*)&As[kk][ty * 4];
            float4 b = *(const float4*)&Bs[kk][tx * 4];
            float aa[4] = {a.x, a.y, a.z, a.w};
            float bb[4] = {b.x, b.y, b.z, b.w};
#pragma unroll
            for (int i = 0; i < 4; ++i)
#pragma unroll
                for (int j = 0; j < 4; ++j)
                    acc[i][j] += aa[i] * bb[j];
        }
    }
#pragma unroll
    for (int i = 0; i < 4; ++i) {
        float4 o = make_float4(acc[i][0], acc[i][1], acc[i][2], acc[i][3]);
        *(float4*)(logits + (long long)(n0 + ty * 4 + i) * VOCAB + (v0 + tx * 4)) = o;
    }
}

// ===================== fused per-row sampler (verified r3) =====================
__global__ __launch_bounds__(1024) void sample_kernel(
        float* __restrict__ probs, const float* __restrict__ temps,
        const float* __restrict__ topps, float* __restrict__ outTok) {
    const int row = blockIdx.x;
    const int tid = (int)threadIdx.x;
    float* L = probs + (long long)row * VOCAB;

    __shared__ float hsum[2048];
    __shared__ uint32_t hcnt[2048];
    __shared__ float wred[16];
    __shared__ float aVal[16];
    __shared__ int aIdx[16];
    __shared__ uint32_t tieList[64];
    __shared__ float sM, sS, sSp, sCarry;
    __shared__ uint32_t sPref, sTsKey, sMt, sTieN;

    const float t = temps[row];
    const float p = topps[row];

    // ---- P1: M = max(l/t)
    float m = -INFINITY;
    for (int i = 0; i < 125; ++i) m = fmaxf(m, L[tid + i * 1024] / t);
    for (int o = 32; o >= 1; o >>= 1) m = fmaxf(m, __shfl_xor(m, o, 64));
    if ((tid & 63) == 0) wred[tid >> 6] = m;
    __syncthreads();
    if (tid == 0) {
        float mm = wred[0];
        for (int w = 1; w < 16; ++w) mm = fmaxf(mm, wred[w]);
        sM = mm;
    }
    __syncthreads();
    const float M = sM;

    // ---- P2: S = sum exp(l/t - M)
    float sacc0 = 0.0f;
    for (int i = 0; i < 125; ++i) sacc0 += expf(L[tid + i * 1024] / t - M);
    for (int o = 32; o >= 1; o >>= 1) sacc0 += __shfl_xor(sacc0, o, 64);
    if ((tid & 63) == 0) wred[tid >> 6] = sacc0;
    __syncthreads();
    if (tid == 0) {
        float ss = 0.0f;
        for (int w = 0; w < 16; ++w) ss += wred[w];
        sS = ss;
    }
    __syncthreads();
    const float S = sS;

    // ---- Level 1: bucket = key >> 20
    for (int i = tid; i < 2048; i += 1024) { hsum[i] = 0.0f; hcnt[i] = 0u; }
    __syncthreads();
    for (int i = 0; i < 125; ++i) {
        int v = tid + i * 1024;
        float pv = expf(L[v] / t - M) / S;
        atomicAdd(&hsum[__float_as_uint(pv) >> 20], pv);
    }
    __syncthreads();
    if (tid == 0) {
        float sa = 0.0f; int cb = -1;
        for (int b = 2047; b >= 0; --b) {
            float h = hsum[b];
            if (sa + h > p) { cb = b; break; }
            sa += h;
        }
        if (cb < 0) { cb = 0; sa -= hsum[0]; }
        sPref = (uint32_t)cb; sCarry = sa;
    }
    __syncthreads();

    // ---- Level 2
    {
        const uint32_t pref1 = sPref;
        hsum[tid & 1023] = 0.0f;
        hcnt[tid & 1023] = 0u;
        __syncthreads();
        for (int i = 0; i < 125; ++i) {
            int v = tid + i * 1024;
            float pv = expf(L[v] / t - M) / S;
            uint32_t key = __float_as_uint(pv);
            if ((key >> 20) == pref1) atomicAdd(&hsum[(key >> 10) & 1023u], pv);
        }
        __syncthreads();
        if (tid == 0) {
            float sa = sCarry; int cb = -1;
            for (int b = 1023; b >= 0; --b) {
                float h = hsum[b];
                if (sa + h > p) { cb = b; break; }
                sa += h;
            }
            if (cb < 0) { cb = 0; sa -= hsum[0]; }
            sPref = (sPref << 10) | (uint32_t)cb; sCarry = sa;
        }
        __syncthreads();
    }

    // ---- Level 3
    {
        const uint32_t pref21 = sPref;
        hsum[tid & 1023] = 0.0f;
        hcnt[tid & 1023] = 0u;
        __syncthreads();
        for (int i = 0; i < 125; ++i) {
            int v = tid + i * 1024;
            float pv = expf(L[v] / t - M) / S;
            uint32_t key = __float_as_uint(pv);
            if ((key >> 10) == pref21) {
                atomicAdd(&hsum[key & 1023u], pv);
                atomicAdd(&hcnt[key & 1023u], 1u);
            }
        }
        __syncthreads();
        if (tid == 0) {
            float sa = sCarry; int cb = -1;
            for (int b = 1023; b >= 0; --b) {
                float h = hsum[b];
                if (sa + h > p) { cb = b; break; }
                sa += h;
            }
            if (cb < 0) { cb = 0; sa -= hsum[0]; }
            uint32_t ts = (sPref << 10) | (uint32_t)cb;
            uint32_t cnt = hcnt[cb]; if (cnt == 0u) cnt = 1u;
            float tf = __uint_as_float(ts);
            uint32_t mt;
            if (!(tf > 0.0f)) mt = cnt;
            else {
                float rem = p - sa; if (rem < 0.0f) rem = 0.0f;
                float q = floorf(rem / tf);
                mt = (q >= (float)(cnt - 1)) ? cnt : ((uint32_t)q + 1u);
            }
            sTsKey = ts; sMt = mt;
            sSp = sa + (float)mt * tf;
            sTieN = 0u;
        }
        __syncthreads();
    }

    // ---- tie index collection
    const uint32_t ts = sTsKey;
    for (int i = 0; i < 125; ++i) {
        int v = tid + i * 1024;
        float pv = expf(L[v] / t - M) / S;
        if (__float_as_uint(pv) == ts) {
            uint32_t pos = atomicAdd(&sTieN, 1u);
            if (pos < 64u) tieList[pos] = (uint32_t)v;
        }
    }
    __syncthreads();

    // ---- final: write probs_f, gumbel-argmax
    const uint32_t mt = sMt;
    const float Sp = sSp;
    const uint32_t tn = min(sTieN, 64u);
    float bestV = -INFINITY;
    int bestI = 0x7FFFFFFF;
    for (int i = 0; i < 125; ++i) {
        int v = tid + i * 1024;
        float pv = expf(L[v] / t - M) / S;
        uint32_t key = __float_as_uint(pv);
        bool kept = key > ts;
        if (key == ts) {
            uint32_t rank = 0;
            for (uint32_t j = 0; j < tn; ++j) rank += (tieList[j] < (uint32_t)v) ? 1u : 0u;
            kept = rank < mt;
        }
        float pf = kept ? pv / Sp : 0.0f;
        L[v] = pf;
        uint32_t jj = (uint32_t)row * (uint32_t)VOCAB + (uint32_t)v;
        float g = jax_gumbel(jax_bits(jj));
        float val = logf(pf + 1e-20f) + g;
        if (val > bestV || (val == bestV && v < bestI)) { bestV = val; bestI = v; }
    }
    for (int o = 32; o >= 1; o >>= 1) {
        float ov = __shfl_xor(bestV, o, 64);
        int oi = __shfl_xor(bestI, o, 64);
        if (ov > bestV || (ov == bestV && oi < bestI)) { bestV = ov; bestI = oi; }
    }
    if ((tid & 63) == 0) { aVal[tid >> 6] = bestV; aIdx[tid >> 6] = bestI; }
    __syncthreads();
    if (tid == 0) {
        float bv = aVal[0]; int bi = aIdx[0];
        for (int w = 1; w < 16; ++w) {
            if (aVal[w] > bv || (aVal[w] == bv && aIdx[w] < bi)) { bv = aVal[w]; bi = aIdx[w]; }
        }
        outTok[row] = (float)bi;
    }
}

// ===================== launch =====================
extern "C" void kernel_launch(void* const* d_in, const int* in_sizes, int n_in,
                              void* d_out, int out_size, void* d_ws, size_t ws_size,
                              hipStream_t stream) {
    const float* hidden = (const float*)d_in[0];
    const float* emb    = (const float*)d_in[1];
    const float* temps  = (const float*)d_in[2];
    const float* topps  = (const float*)d_in[3];
    const int*   idx    = (const int*)d_in[4];

    float* probs  = (float*)d_out;        // [N,V]: logits, then probs_f in place
    float* outTok = probs + NV_ELEMS;     // [N] tokens as f32

    if (ws_size >= (size_t)(1 << 20)) {
        ushort* wsA = (ushort*)d_ws;      // 16 x 64 KB pre-swizzled A images
        prep_a<<<N_TOK, 256, 0, stream>>>(hidden, idx, wsA);
        gemm_mfma<<<VOCAB / 64, 256, 0, stream>>>(wsA, emb, probs);
    } else {
        gemm_kernel<<<dim3(4, 2000), 256, 0, stream>>>(hidden, idx, emb, probs);
    }
    sample_kernel<<<N_TOK, 1024, 0, stream>>>(probs, temps, topps, outTok);
}

// Round 5
// 584.376 us; speedup vs baseline: 2.9035x; 1.9835x over previous
//
#include <hip/hip_runtime.h>
#include <stdint.h>

#define N_TOK 256
#define D_MODEL 1024
#define VOCAB 128000
#define NV_ELEMS (256LL * 128000LL)
#define LIST_CAP 24576

typedef __attribute__((ext_vector_type(8))) short bfrag;   // 8 bf16 (4 VGPR)
typedef __attribute__((ext_vector_type(4))) float facc;    // 4 f32

// ===================== helpers =====================
__device__ __forceinline__ uint32_t bf16_rne_bits(float x) {
    uint32_t u = __float_as_uint(x);
    return (u + 0x7fffu + ((u >> 16) & 1u)) >> 16;
}

__device__ __forceinline__ uint32_t rotl32(uint32_t x, int d) {
    return (x << d) | (x >> (32 - d));
}

// JAX threefry2x32, key=(0,42) (KAT-verified core)
__device__ __forceinline__ uint2 tf_0_42(uint32_t c0, uint32_t c1) {
    const uint32_t ks0 = 0u, ks1 = 42u, ks2 = 0x1BD11BDAu ^ 42u;
    uint32_t x0 = c0 + ks0, x1 = c1 + ks1;
#define R4(a,b,c,d) \
    x0 += x1; x1 = rotl32(x1,a); x1 ^= x0; \
    x0 += x1; x1 = rotl32(x1,b); x1 ^= x0; \
    x0 += x1; x1 = rotl32(x1,c); x1 ^= x0; \
    x0 += x1; x1 = rotl32(x1,d); x1 ^= x0;
    R4(13,15,26,6)   x0 += ks1; x1 += ks2 + 1u;
    R4(17,29,16,24)  x0 += ks2; x1 += ks0 + 2u;
    R4(13,15,26,6)   x0 += ks0; x1 += ks1 + 3u;
    R4(17,29,16,24)  x0 += ks1; x1 += ks2 + 4u;
    R4(13,15,26,6)   x0 += ks2; x1 += ks0 + 5u;
#undef R4
    return make_uint2(x0, x1);
}

// partitionable threefry bits: counter=(0,j), out = x^y (verified r3)
__device__ __forceinline__ uint32_t jax_bits(uint32_t j) {
    uint2 r = tf_0_42(0u, j);
    return r.x ^ r.y;
}

__device__ __forceinline__ float jax_gumbel(uint32_t bits) {
    const float TINY = 1.17549435e-38f;
    float u = __uint_as_float((bits >> 9) | 0x3f800000u) - 1.0f;
    u = u + TINY;
    u = fmaxf(TINY, u);
    return -__logf(-__logf(u));
}

// raw prob: rv = exp(l * (1/t)); identical callsite function in every pass
__device__ __forceinline__ float rv_of(float l, float rinv) {
    return __expf(l * rinv);
}

// async 16B global->LDS (dest = lbase + lane*16); g must include lane*16
__device__ __forceinline__ void async_copy16(const void* g, void* lbase, int lane) {
#if defined(__has_builtin) && __has_builtin(__builtin_amdgcn_global_load_lds)
    __builtin_amdgcn_global_load_lds((const uint32_t*)g, (uint32_t*)lbase, 16, 0, 0);
#else
    *(bfrag*)((char*)lbase + lane * 16) = *(const bfrag*)g;
#endif
}

// ============ A pre-convert (gather + split-bf16 + swizzled image, BK=32) ====
// per 32-k K-tile (32768 B): row r, kgroup g(0..3), sel(hi=0,lo=16), elem e:
//   byte = kt*32768 + ((r*128 + g*32 + sel) ^ ((r&7)<<4)) + e*2
__global__ __launch_bounds__(256) void prep_a(
        const float* __restrict__ hidden, const int* __restrict__ idx,
        ushort* __restrict__ wsA) {
    const int m = blockIdx.x;
    const int t = threadIdx.x;
    const float* src = hidden + (long long)idx[m] * D_MODEL;
    const uint32_t swz = (uint32_t)((m & 7) << 4);
    for (int j = 0; j < 4; ++j) {
        int k = t * 4 + j;
        float x = src[k];
        uint32_t hb = bf16_rne_bits(x);
        float hf = __uint_as_float(hb << 16);
        uint32_t lb = bf16_rne_bits(x - hf);
        int kt = k >> 5, kk = k & 31, g = kk >> 3, e = kk & 7;
        char* img = (char*)wsA + (size_t)kt * 32768;
        uint32_t base = (uint32_t)(m * 128 + g * 32);
        *(ushort*)(img + ((base + 0) ^ swz) + e * 2) = (ushort)hb;
        *(ushort*)(img + ((base + 16) ^ swz) + e * 2) = (ushort)lb;
    }
}

// ===================== split-bf16 MFMA GEMM (BM=256,BN=64,BK=32) ============
__global__ __launch_bounds__(256) void gemm_mfma(
        const ushort* __restrict__ wsA, const float* __restrict__ emb,
        float* __restrict__ logits) {
    __shared__ __align__(16) ushort Aimg[16384];  // 32 KB swizzled A K-tile
    __shared__ __align__(16) ushort Bimg[4096];   // 8 KB swizzled B K-tile
    const int tid = (int)threadIdx.x;
    const int w = tid >> 6, l = tid & 63;
    const int lr = l & 15, lg = l >> 4;
    const int v0 = blockIdx.x * 64;
    char* Ab = (char*)Aimg;
    char* Bb = (char*)Bimg;

    facc acc[4][4] = {};

    for (int kt = 0; kt < 32; ++kt) {
        __syncthreads();
        // stage A: async linear copy of pre-swizzled 32 KB image
        const char* asrc = (const char*)wsA + (size_t)kt * 32768;
#pragma unroll
        for (int i = 0; i < 8; ++i) {
            int off = w * 8192 + i * 1024;
            async_copy16(asrc + off + l * 16, Ab + off, l);
        }
        // stage B: 64 rows x 32 k, f32 -> bf16 hi/lo, swizzled b128 writes
        {
            int rb = tid >> 2, g = tid & 3;
            const float* bs = emb + (size_t)(v0 + rb) * D_MODEL + kt * 32 + g * 8;
            float4 x0 = *(const float4*)bs;
            float4 x1 = *(const float4*)(bs + 4);
            float xs[8] = {x0.x, x0.y, x0.z, x0.w, x1.x, x1.y, x1.z, x1.w};
            bfrag h, lo;
#pragma unroll
            for (int e = 0; e < 8; ++e) {
                uint32_t hb = bf16_rne_bits(xs[e]);
                float hf = __uint_as_float(hb << 16);
                uint32_t lb = bf16_rne_bits(xs[e] - hf);
                h[e] = (short)hb; lo[e] = (short)lb;
            }
            uint32_t swz = (uint32_t)((rb & 7) << 4);
            uint32_t base = (uint32_t)(rb * 128 + g * 32);
            *(bfrag*)(Bb + ((base + 0) ^ swz)) = h;
            *(bfrag*)(Bb + ((base + 16) ^ swz)) = lo;
        }
        __syncthreads();
        // MFMA: k-group per lane = lg (K=32 per kt)
        bfrag bh[4], bl[4];
#pragma unroll
        for (int nj = 0; nj < 4; ++nj) {
            int rb = nj * 16 + lr;
            uint32_t swz = (uint32_t)((rb & 7) << 4);
            uint32_t base = (uint32_t)(rb * 128 + lg * 32);
            bh[nj] = *(const bfrag*)(Bb + ((base + 0) ^ swz));
            bl[nj] = *(const bfrag*)(Bb + ((base + 16) ^ swz));
        }
#pragma unroll
        for (int mi = 0; mi < 4; ++mi) {
            int r = w * 64 + mi * 16 + lr;
            uint32_t swz = (uint32_t)((r & 7) << 4);
            uint32_t base = (uint32_t)(r * 128 + lg * 32);
            bfrag ah = *(const bfrag*)(Ab + ((base + 0) ^ swz));
            bfrag al = *(const bfrag*)(Ab + ((base + 16) ^ swz));
#pragma unroll
            for (int nj = 0; nj < 4; ++nj) {
                acc[mi][nj] = __builtin_amdgcn_mfma_f32_16x16x32_bf16(ah, bh[nj], acc[mi][nj], 0, 0, 0);
                acc[mi][nj] = __builtin_amdgcn_mfma_f32_16x16x32_bf16(ah, bl[nj], acc[mi][nj], 0, 0, 0);
                acc[mi][nj] = __builtin_amdgcn_mfma_f32_16x16x32_bf16(al, bh[nj], acc[mi][nj], 0, 0, 0);
            }
        }
    }
    // C write: row = w*64 + mi*16 + lg*4 + reg, col = v0 + nj*16 + lr
#pragma unroll
    for (int mi = 0; mi < 4; ++mi) {
        int mbase = w * 64 + mi * 16 + lg * 4;
#pragma unroll
        for (int nj = 0; nj < 4; ++nj) {
            int v = v0 + nj * 16 + lr;
#pragma unroll
            for (int reg = 0; reg < 4; ++reg)
                logits[(size_t)(mbase + reg) * VOCAB + v] = acc[mi][nj][reg];
        }
    }
}

// ===================== f32 GEMM fallback (ws too small) =====================
__global__ __launch_bounds__(256) void gemm_kernel(
        const float* __restrict__ hidden, const int* __restrict__ idx,
        const float* __restrict__ emb, float* __restrict__ logits) {
    __shared__ float As[16][64];
    __shared__ float Bs[16][64];
    const int n0 = blockIdx.x * 64, v0 = blockIdx.y * 64;
    const int tid = threadIdx.x;
    const int tx = tid & 15, ty = tid >> 4;
    const int lr = tid >> 2, lk = (tid & 3) * 4;
    float acc[4][4] = {};
    const long long aRow = (long long)idx[n0 + lr] * D_MODEL + lk;
    const long long bRow = (long long)(v0 + lr) * D_MODEL + lk;
    for (int k0 = 0; k0 < D_MODEL; k0 += 16) {
        float4 av = *(const float4*)(hidden + aRow + k0);
        float4 bv = *(const float4*)(emb + bRow + k0);
        __syncthreads();
        As[lk + 0][lr] = av.x; As[lk + 1][lr] = av.y; As[lk + 2][lr] = av.z; As[lk + 3][lr] = av.w;
        Bs[lk + 0][lr] = bv.x; Bs[lk + 1][lr] = bv.y; Bs[lk + 2][lr] = bv.z; Bs[lk + 3][lr] = bv.w;
        __syncthreads();
#pragma unroll
        for (int kk = 0; kk < 16; ++kk) {
            float4 a = *(const float4*)&As[kk][ty * 4];
            float4 b = *(const float4*)&Bs[kk][tx * 4];
            float aa[4] = {a.x, a.y, a.z, a.w};
            float bb[4] = {b.x, b.y, b.z, b.w};
#pragma unroll
            for (int i = 0; i < 4; ++i)
#pragma unroll
                for (int j = 0; j < 4; ++j)
                    acc[i][j] += aa[i] * bb[j];
        }
    }
#pragma unroll
    for (int i = 0; i < 4; ++i) {
        float4 o = make_float4(acc[i][0], acc[i][1], acc[i][2], acc[i][3]);
        *(float4*)(logits + (long long)(n0 + ty * 4 + i) * VOCAB + (v0 + tx * 4)) = o;
    }
}

// ===================== fused per-row sampler (raw-domain, 3 passes) ==========
// wave0-cooperative descending scan; semantics match r3's serial scan:
//   sa=carry; for b=nb-1..0: if (sa+h[b] > P) {cb=b; stop} else sa+=h[b];
//   no crossing: cb=0, sa = carry + sum(all) - h[0]
__device__ __forceinline__ void scan_desc_wave(const float* h, int nb, float carry,
                                               float P, int* outCb, float* outSa) {
    int lane = (int)threadIdx.x & 63;
    int chunk = nb >> 6;
    int top = nb - 1 - lane * chunk;
    float ls = 0.0f;
    for (int j = 0; j < chunk; ++j) ls += h[top - j];
    float incl = ls;
    for (int o = 1; o < 64; o <<= 1) {
        float v = __shfl_up(incl, o, 64);
        if (lane >= o) incl += v;
    }
    float s0 = carry + incl - ls;
    unsigned long long mask = __ballot(s0 + ls > P);
    if (mask == 0ull) {
        if (lane == 63) { *outCb = 0; *outSa = carry + incl - h[0]; }
    } else {
        int cstar = (int)__builtin_ctzll(mask);
        if (lane == cstar) {
            float sa = s0; int cb = 0;
            for (int j = 0; j < chunk; ++j) {
                int b = top - j;
                if (sa + h[b] > P) { cb = b; break; }
                sa += h[b];
            }
            *outCb = cb; *outSa = sa;
        }
    }
}

__global__ __launch_bounds__(1024) void sample_kernel(
        float* __restrict__ probs, const float* __restrict__ temps,
        const float* __restrict__ topps, float* __restrict__ outTok) {
    const int row = blockIdx.x;
    const int tid = (int)threadIdx.x;
    float* L = probs + (long long)row * VOCAB;
    const float4* L4 = (const float4*)L;
    float4* L4w = (float4*)L;

    __shared__ float waveH[16][2048];          // 128 KB; keys list aliases [4..]
    __shared__ float hsum[2048];               // 8 KB
    __shared__ uint32_t hcnt[1024];            // 4 KB
    __shared__ float wred[16];
    __shared__ float aVal[16];
    __shared__ int aIdx[16];
    __shared__ uint32_t tieList[256];
    __shared__ int sCb;
    __shared__ float sSa;
    __shared__ float sP, sCarry1, sCarry2, sSp, sInvSp;
    __shared__ uint32_t sPref1, sCb2, sTsKey, sMt, sTieN, sCnt;
    uint32_t* keys = (uint32_t*)&waveH[4][0];  // 96 KB -> LIST_CAP u32

    const float t = temps[row];
    const float p = topps[row];
    const float rinv = 1.0f / t;

    // ---- Pass A: per-wave histograms of raw mass, bucket = key>>20
    for (int i = tid; i < 16 * 2048; i += 1024) ((float*)waveH)[i] = 0.0f;
    __syncthreads();
    {
        float* myH = waveH[tid >> 6];
#pragma unroll 2
        for (int i = 0; i < 31; ++i) {
            float4 x = L4[tid + i * 1024];
            float r0 = rv_of(x.x, rinv), r1 = rv_of(x.y, rinv);
            float r2 = rv_of(x.z, rinv), r3 = rv_of(x.w, rinv);
            atomicAdd(&myH[__float_as_uint(r0) >> 20], r0);
            atomicAdd(&myH[__float_as_uint(r1) >> 20], r1);
            atomicAdd(&myH[__float_as_uint(r2) >> 20], r2);
            atomicAdd(&myH[__float_as_uint(r3) >> 20], r3);
        }
        if (tid < 256) {
            float4 x = L4[31744 + tid];
            float r0 = rv_of(x.x, rinv), r1 = rv_of(x.y, rinv);
            float r2 = rv_of(x.z, rinv), r3 = rv_of(x.w, rinv);
            atomicAdd(&myH[__float_as_uint(r0) >> 20], r0);
            atomicAdd(&myH[__float_as_uint(r1) >> 20], r1);
            atomicAdd(&myH[__float_as_uint(r2) >> 20], r2);
            atomicAdd(&myH[__float_as_uint(r3) >> 20], r3);
        }
    }
    __syncthreads();
    // merge 16 wave-hists -> hsum (thread handles buckets tid, tid+1024)
    {
        float a0 = 0.0f, a1 = 0.0f;
#pragma unroll
        for (int w2 = 0; w2 < 16; ++w2) { a0 += waveH[w2][tid]; a1 += waveH[w2][tid + 1024]; }
        hsum[tid] = a0; hsum[tid + 1024] = a1;
        // block-reduce total raw mass (deterministic tree)
        float s = a0 + a1;
        for (int o = 32; o >= 1; o >>= 1) s += __shfl_xor(s, o, 64);
        if ((tid & 63) == 0) wred[tid >> 6] = s;
    }
    __syncthreads();
    if (tid == 0) {
        float tot = 0.0f;
        for (int w2 = 0; w2 < 16; ++w2) tot += wred[w2];
        sP = p * tot;
    }
    __syncthreads();
    if (tid < 64) scan_desc_wave(hsum, 2048, 0.0f, sP, &sCb, &sSa);
    __syncthreads();
    if (tid == 0) { sPref1 = (uint32_t)sCb; sCarry1 = sSa; sCnt = 0u; }
    __syncthreads();

    // ---- Pass B: compact keys of the cut L1 bucket
    const uint32_t pref1 = sPref1;
    const float P = sP;
#pragma unroll 2
    for (int i = 0; i < 31; ++i) {
        float4 x = L4[tid + i * 1024];
        float rr[4] = {rv_of(x.x, rinv), rv_of(x.y, rinv), rv_of(x.z, rinv), rv_of(x.w, rinv)};
#pragma unroll
        for (int c = 0; c < 4; ++c) {
            uint32_t key = __float_as_uint(rr[c]);
            if ((key >> 20) == pref1) {
                uint32_t pos = atomicAdd(&sCnt, 1u);
                if (pos < LIST_CAP) keys[pos] = key;
            }
        }
    }
    if (tid < 256) {
        float4 x = L4[31744 + tid];
        float rr[4] = {rv_of(x.x, rinv), rv_of(x.y, rinv), rv_of(x.z, rinv), rv_of(x.w, rinv)};
#pragma unroll
        for (int c = 0; c < 4; ++c) {
            uint32_t key = __float_as_uint(rr[c]);
            if ((key >> 20) == pref1) {
                uint32_t pos = atomicAdd(&sCnt, 1u);
                if (pos < LIST_CAP) keys[pos] = key;
            }
        }
    }
    __syncthreads();
    const uint32_t K = sCnt;
    const bool inLds = (K <= LIST_CAP);

    // ---- Level 2 (bucket = (key>>10)&1023)
    if (tid < 1024) hsum[tid] = 0.0f;
    __syncthreads();
    if (inLds) {
        for (uint32_t j = tid; j < K; j += 1024) {
            uint32_t key = keys[j];
            atomicAdd(&hsum[(key >> 10) & 1023u], __uint_as_float(key));
        }
    } else {
        for (int i = 0; i < 125; ++i) {
            int v = tid + i * 1024;
            float rv = rv_of(L[v], rinv);
            uint32_t key = __float_as_uint(rv);
            if ((key >> 20) == pref1) atomicAdd(&hsum[(key >> 10) & 1023u], rv);
        }
    }
    __syncthreads();
    if (tid < 64) scan_desc_wave(hsum, 1024, sCarry1, P, &sCb, &sSa);
    __syncthreads();
    if (tid == 0) { sCb2 = (uint32_t)sCb; sCarry2 = sSa; }
    __syncthreads();

    // ---- Level 3 (bucket = key&1023, with counts)
    const uint32_t cb2 = sCb2;
    if (tid < 1024) { hsum[tid] = 0.0f; hcnt[tid] = 0u; }
    __syncthreads();
    if (inLds) {
        for (uint32_t j = tid; j < K; j += 1024) {
            uint32_t key = keys[j];
            if (((key >> 10) & 1023u) == cb2) {
                atomicAdd(&hsum[key & 1023u], __uint_as_float(key));
                atomicAdd(&hcnt[key & 1023u], 1u);
            }
        }
    } else {
        const uint32_t pref2full = (pref1 << 10) | cb2;
        for (int i = 0; i < 125; ++i) {
            int v = tid + i * 1024;
            float rv = rv_of(L[v], rinv);
            uint32_t key = __float_as_uint(rv);
            if ((key >> 10) == pref2full) {
                atomicAdd(&hsum[key & 1023u], rv);
                atomicAdd(&hcnt[key & 1023u], 1u);
            }
        }
    }
    __syncthreads();
    if (tid < 64) scan_desc_wave(hsum, 1024, sCarry2, P, &sCb, &sSa);
    __syncthreads();
    if (tid == 0) {
        int cb3 = sCb; float sa3 = sSa;
        uint32_t ts = (pref1 << 20) | (cb2 << 10) | (uint32_t)cb3;
        uint32_t cnt = hcnt[cb3]; if (cnt == 0u) cnt = 1u;
        float tf = __uint_as_float(ts);
        uint32_t mt;
        float rem = P - sa3; if (rem < 0.0f) rem = 0.0f;
        if (!(tf > 0.0f)) mt = cnt;
        else {
            float q = floorf(rem / tf);
            mt = (q >= (float)(cnt - 1)) ? cnt : ((uint32_t)q + 1u);
        }
        float Sp = sa3 + (float)mt * tf;
        sTsKey = ts; sMt = mt; sSp = Sp; sInvSp = 1.0f / Sp; sTieN = 0u;
    }
    __syncthreads();

    // ---- Pass C: write probs_f + gumbel-argmax (ties deferred)
    const uint32_t ts = sTsKey, mt = sMt;
    const float invSp = sInvSp;
    float bestV = -INFINITY;
    int bestI = 0x7FFFFFFF;
    const uint32_t rowBase = (uint32_t)row * (uint32_t)VOCAB;
    for (int i = 0; i < 32; ++i) {
        int f4i = (i < 31) ? (tid + i * 1024) : (31744 + tid);
        if (i == 31 && tid >= 256) break;
        float4 x = L4[f4i];
        float rr[4] = {rv_of(x.x, rinv), rv_of(x.y, rinv), rv_of(x.z, rinv), rv_of(x.w, rinv)};
        float4 out;
        float* op = (float*)&out;
#pragma unroll
        for (int c = 0; c < 4; ++c) {
            uint32_t key = __float_as_uint(rr[c]);
            int v = f4i * 4 + c;
            if (key > ts) {
                float pf = rr[c] * invSp;
                op[c] = pf;
                float g = jax_gumbel(jax_bits(rowBase + (uint32_t)v));
                float val = __logf(pf + 1e-20f) + g;
                if (val > bestV || (val == bestV && v < bestI)) { bestV = val; bestI = v; }
            } else if (key == ts) {
                op[c] = 0.0f;   // placeholder; fixed after barrier
                uint32_t pos = atomicAdd(&sTieN, 1u);
                if (pos < 256u) tieList[pos] = (uint32_t)v;
            } else {
                op[c] = 0.0f;   // zeroed: argmax-irrelevant (needs gumbel > 46)
            }
        }
        L4w[f4i] = out;
    }
    __syncthreads();
    // tie fix-up: rank by index among ties (order-independent)
    {
        const uint32_t tn = min(sTieN, 256u);
        if ((uint32_t)tid < tn) {
            uint32_t v = tieList[tid];
            uint32_t rank = 0;
            for (uint32_t j = 0; j < tn; ++j) rank += (tieList[j] < v) ? 1u : 0u;
            if (rank < mt) {
                float pf = __uint_as_float(ts) * invSp;
                L[v] = pf;
                float g = jax_gumbel(jax_bits(rowBase + v));
                float val = __logf(pf + 1e-20f) + g;
                if (val > bestV || (val == bestV && (int)v < bestI)) { bestV = val; bestI = (int)v; }
            }
        }
    }
    // block argmax reduce
    for (int o = 32; o >= 1; o >>= 1) {
        float ov = __shfl_xor(bestV, o, 64);
        int oi = __shfl_xor(bestI, o, 64);
        if (ov > bestV || (ov == bestV && oi < bestI)) { bestV = ov; bestI = oi; }
    }
    if ((tid & 63) == 0) { aVal[tid >> 6] = bestV; aIdx[tid >> 6] = bestI; }
    __syncthreads();
    if (tid == 0) {
        float bv = aVal[0]; int bi = aIdx[0];
        for (int w2 = 1; w2 < 16; ++w2) {
            if (aVal[w2] > bv || (aVal[w2] == bv && aIdx[w2] < bi)) { bv = aVal[w2]; bi = aIdx[w2]; }
        }
        outTok[row] = (float)bi;
    }
}

// ===================== launch =====================
extern "C" void kernel_launch(void* const* d_in, const int* in_sizes, int n_in,
                              void* d_out, int out_size, void* d_ws, size_t ws_size,
                              hipStream_t stream) {
    const float* hidden = (const float*)d_in[0];
    const float* emb    = (const float*)d_in[1];
    const float* temps  = (const float*)d_in[2];
    const float* topps  = (const float*)d_in[3];
    const int*   idx    = (const int*)d_in[4];

    float* probs  = (float*)d_out;        // [N,V]: logits, then probs_f in place
    float* outTok = probs + NV_ELEMS;     // [N] tokens as f32

    if (ws_size >= (size_t)(1 << 20)) {
        ushort* wsA = (ushort*)d_ws;      // 32 x 32 KB pre-swizzled A images
        prep_a<<<N_TOK, 256, 0, stream>>>(hidden, idx, wsA);
        gemm_mfma<<<VOCAB / 64, 256, 0, stream>>>(wsA, emb, probs);
    } else {
        gemm_kernel<<<dim3(4, 2000), 256, 0, stream>>>(hidden, idx, emb, probs);
    }
    sample_kernel<<<N_TOK, 1024, 0, stream>>>(probs, temps, topps, outTok);
}